// Round 5
// baseline (332.494 us; speedup 1.0000x reference)
//
#include <hip/hip_runtime.h>

typedef __bf16 bf16_t;
typedef __bf16 bf16x8 __attribute__((ext_vector_type(8)));
typedef __bf16 bf16x4 __attribute__((ext_vector_type(4)));
typedef float f32x4 __attribute__((ext_vector_type(4)));

static constexpr int Bb = 4, Hh = 12, Nn = 1024, Cc = 768, HD = 64;
static constexpr int OUT0 = Bb * Nn * Cc;  // 3145728 floats

// ---------------- convert fp32 -> bf16 (x, qkv_w, proj_w) ----------------
__global__ __launch_bounds__(256) void convert_all(
    const float* __restrict__ x, const float* __restrict__ qw, const float* __restrict__ pw,
    bf16_t* __restrict__ xb, bf16_t* __restrict__ qwb, bf16_t* __restrict__ pwb) {
  const int NX = (Bb * Nn * Cc) / 4;  // 786432 float4s
  const int NQ = (3 * Cc * Cc) / 4;   // 442368
  int i = blockIdx.x * 256 + threadIdx.x;
  const float4* src;
  bf16_t* dst;
  int off;
  if (i < NX) { src = (const float4*)x; dst = xb; off = i; }
  else if (i < NX + NQ) { src = (const float4*)qw; dst = qwb; off = i - NX; }
  else { src = (const float4*)pw; dst = pwb; off = i - NX - NQ; }
  float4 v = src[off];
  bf16x4 o;
  o[0] = (bf16_t)v.x; o[1] = (bf16_t)v.y; o[2] = (bf16_t)v.z; o[3] = (bf16_t)v.w;
  *(bf16x4*)(dst + (size_t)off * 4) = o;
}

// ---------------- 128x128-tile bf16 MFMA GEMM (qkv projection) -----------
template <int MODE>
__global__ __launch_bounds__(256) void gemm_bt(
    const bf16_t* __restrict__ A, const bf16_t* __restrict__ Bm, int N, int K,
    bf16_t* __restrict__ q_bf, bf16_t* __restrict__ k_bf, bf16_t* __restrict__ vT_bf,
    float* __restrict__ outF, const float* __restrict__ bias) {
  __shared__ bf16_t As[128 * 40];
  __shared__ bf16_t Bs[128 * 40];
  const int tid = threadIdx.x;
  const int lane = tid & 63;
  const int w = tid >> 6;
  const int wr = w >> 1, wc = w & 1;
  const int g = lane >> 4, r = lane & 15;
  const int ntiles = N >> 7;
  const int m0 = (blockIdx.x / ntiles) << 7;
  const int n0 = (blockIdx.x % ntiles) << 7;

  const f32x4 fz = {0.f, 0.f, 0.f, 0.f};
  f32x4 acc[4][4];
#pragma unroll
  for (int i = 0; i < 4; i++)
#pragma unroll
    for (int j = 0; j < 4; j++) acc[i][j] = fz;

  for (int k0 = 0; k0 < K; k0 += 32) {
#pragma unroll
    for (int p = 0; p < 2; p++) {
      int idx = tid + (p << 8);
      int row = idx >> 2;
      int kof = (idx & 3) << 3;
      *(bf16x8*)&As[row * 40 + kof] = *(const bf16x8*)&A[(size_t)(m0 + row) * K + k0 + kof];
      *(bf16x8*)&Bs[row * 40 + kof] = *(const bf16x8*)&Bm[(size_t)(n0 + row) * K + k0 + kof];
    }
    __syncthreads();
    bf16x8 af[4], bfv[4];
#pragma unroll
    for (int i = 0; i < 4; i++) af[i] = *(const bf16x8*)&As[(wr * 64 + i * 16 + r) * 40 + g * 8];
#pragma unroll
    for (int j = 0; j < 4; j++) bfv[j] = *(const bf16x8*)&Bs[(wc * 64 + j * 16 + r) * 40 + g * 8];
#pragma unroll
    for (int i = 0; i < 4; i++)
#pragma unroll
      for (int j = 0; j < 4; j++)
        acc[i][j] = __builtin_amdgcn_mfma_f32_16x16x32_bf16(af[i], bfv[j], acc[i][j], 0, 0, 0);
    __syncthreads();
  }

#pragma unroll
  for (int i = 0; i < 4; i++) {
#pragma unroll
    for (int j = 0; j < 4; j++) {
      int c = n0 + wc * 64 + j * 16 + r;
#pragma unroll
      for (int e = 0; e < 4; e++) {
        int mrow = m0 + wr * 64 + i * 16 + g * 4 + e;
        float val = acc[i][j][e];
        if constexpr (MODE == 0) {
          int which = c / 768;
          int cc = c - which * 768;
          int h = cc >> 6, d = cc & 63;
          int b = mrow >> 10, n = mrow & 1023;
          size_t bh = (size_t)(b * Hh + h);
          if (which == 0)      q_bf[(bh * Nn + n) * HD + d] = (bf16_t)val;
          else if (which == 1) k_bf[(bh * Nn + n) * HD + d] = (bf16_t)val;
          else                 vT_bf[(bh * HD + d) * Nn + n] = (bf16_t)val;
        } else {
          outF[(size_t)mrow * N + c] = val + bias[c];
        }
      }
    }
  }
}

// ---------------- per-(b,h,n) bias MLP -> {1+b0, b1, -b2/N, 0} -----------
__global__ __launch_bounds__(256) void bias_mlp(
    const bf16_t* __restrict__ qb, const bf16_t* __restrict__ kb,
    const float* __restrict__ w1, const float* __restrict__ b1,
    const float* __restrict__ w2, const float* __restrict__ b2,
    float* __restrict__ bias4) {
  __shared__ float w1s[32 * 129];
  __shared__ float qks[8][128];
  __shared__ float h1s[8][32];
  const int t = threadIdx.x;
#pragma unroll
  for (int p = 0; p < 16; p++) {
    int idx = p * 256 + t;
    w1s[(idx >> 7) * 129 + (idx & 127)] = w1[idx];
  }
  const int rl = t >> 5, u = t & 31;
  const int rowg = blockIdx.x * 8 + rl;
  {
    int i4 = u * 4;
    const bf16_t* src = (i4 < 64) ? (qb + (size_t)rowg * HD + i4)
                                  : (kb + (size_t)rowg * HD + (i4 - 64));
    bf16x4 vv = *(const bf16x4*)src;
#pragma unroll
    for (int z = 0; z < 4; z++) qks[rl][i4 + z] = (float)vv[z];
  }
  __syncthreads();
  float accv = b1[u];
#pragma unroll 8
  for (int i = 0; i < 128; i++) accv += qks[rl][i] * w1s[u * 129 + i];
  h1s[rl][u] = fmaxf(accv, 0.f);
  __syncthreads();
  if (u < 4) {
    float outv = 0.f;
    if (u < 3) {
      float s = b2[u];
#pragma unroll
      for (int j = 0; j < 32; j++) s += w2[u * 32 + j] * h1s[rl][j];
      float v = fabsf(s);
      outv = (u == 0) ? (1.f + v) : ((u == 1) ? v : -v * (1.f / (float)Nn));
    }
    bias4[(size_t)rowg * 4 + u] = outv;
  }
}

// ---------------- vsum[b][h*64+d] = sum_n v[b,h,n,d] (one wave each) -----
__global__ __launch_bounds__(256) void vsum_k(
    const bf16_t* __restrict__ vT, float* __restrict__ vsum) {
  const int wid = (blockIdx.x * 256 + threadIdx.x) >> 6;  // 0..3071
  const int lane = threadIdx.x & 63;
  const int b = wid / 768, c = wid % 768;
  const int h = c >> 6, d = c & 63;
  const bf16_t* vp = vT + ((size_t)((b * Hh + h) * HD + d)) * Nn + lane * 16;
  bf16x8 v0 = *(const bf16x8*)vp;
  bf16x8 v1 = *(const bf16x8*)(vp + 8);
  float s = 0.f;
#pragma unroll
  for (int j = 0; j < 8; j++) s += (float)v0[j] + (float)v1[j];
#pragma unroll
  for (int sh = 1; sh < 64; sh <<= 1) s += __shfl_xor(s, sh, 64);
  if (lane == 0) vsum[wid] = s;
}

// ---------------- flash: QK^T -> softmax -> cur write + O1 = cur@v -------
// 4 waves/block, each wave an independent 16-row tile; no __syncthreads.
__global__ __launch_bounds__(256, 4) void flash_cur(
    const bf16_t* __restrict__ qb, const bf16_t* __restrict__ kb,
    const bf16_t* __restrict__ vT, float* __restrict__ cur,
    bf16_t* __restrict__ O1) {
  __shared__ bf16_t Pbs[4][16 * 72];  // per-wave bf16 P tile, row pad 72
  const int w = threadIdx.x >> 6, lane = threadIdx.x & 63;
  const int tile = (blockIdx.x << 2) + w;  // 0..3071
  const int bh = tile >> 6, mt = tile & 63;
  const int g = lane >> 4, r = lane & 15;
  const int row0 = mt << 4;
  const float scale = 0.125f;

  const bf16_t* qp = qb + ((size_t)bh * Nn + row0) * HD;
  const bf16_t* kp = kb + (size_t)bh * Nn * HD;
  const bf16_t* vp = vT + (size_t)bh * HD * Nn;
  bf16x8 a0 = *(const bf16x8*)&qp[r * HD + g * 8];
  bf16x8 a1 = *(const bf16x8*)&qp[r * HD + g * 8 + 32];

  const f32x4 fz = {0.f, 0.f, 0.f, 0.f};
  float m_[4] = {-3.0e38f, -3.0e38f, -3.0e38f, -3.0e38f};
  float s_[4] = {0.f, 0.f, 0.f, 0.f};

  // ---- pass 1: online max + sum ----
  for (int t = 0; t < 16; t++) {
    const int c0 = t << 6;
    f32x4 l[4];
#pragma unroll
    for (int sub = 0; sub < 4; sub++) {
      const bf16_t* kr = &kp[(size_t)(c0 + (sub << 4) + r) * HD + g * 8];
      bf16x8 b0 = *(const bf16x8*)kr;
      bf16x8 b1 = *(const bf16x8*)(kr + 32);
      f32x4 z = __builtin_amdgcn_mfma_f32_16x16x32_bf16(a0, b0, fz, 0, 0, 0);
      l[sub] = __builtin_amdgcn_mfma_f32_16x16x32_bf16(a1, b1, z, 0, 0, 0);
    }
    float tm[4];
#pragma unroll
    for (int e = 0; e < 4; e++) {
      float v0 = fmaxf(l[0][e], l[1][e]);
      float v1 = fmaxf(l[2][e], l[3][e]);
      tm[e] = fmaxf(v0, v1) * scale;
    }
#pragma unroll
    for (int sh = 1; sh < 16; sh <<= 1)
#pragma unroll
      for (int e = 0; e < 4; e++) tm[e] = fmaxf(tm[e], __shfl_xor(tm[e], sh, 64));
    float ts[4];
#pragma unroll
    for (int e = 0; e < 4; e++) {
      float nm = fmaxf(m_[e], tm[e]);
      float f = __expf(m_[e] - nm);
      float sum = __expf(l[0][e] * scale - nm) + __expf(l[1][e] * scale - nm) +
                  __expf(l[2][e] * scale - nm) + __expf(l[3][e] * scale - nm);
      ts[e] = sum;
      m_[e] = nm;
      s_[e] = s_[e] * f;
    }
#pragma unroll
    for (int sh = 1; sh < 16; sh <<= 1)
#pragma unroll
      for (int e = 0; e < 4; e++) ts[e] += __shfl_xor(ts[e], sh, 64);
#pragma unroll
    for (int e = 0; e < 4; e++) s_[e] += ts[e];
  }
  float inv[4];
#pragma unroll
  for (int e = 0; e < 4; e++) inv[e] = 1.f / s_[e];

  // ---- pass 2: recompute, write cur, PV accumulate ----
  float* cp = cur + (size_t)bh * Nn * Nn + (size_t)row0 * Nn;
  bf16_t* pb = Pbs[w];
  f32x4 oacc[4] = {fz, fz, fz, fz};
  for (int t = 0; t < 16; t++) {
    const int c0 = t << 6;
    f32x4 l[4];
#pragma unroll
    for (int sub = 0; sub < 4; sub++) {
      const bf16_t* kr = &kp[(size_t)(c0 + (sub << 4) + r) * HD + g * 8];
      bf16x8 b0 = *(const bf16x8*)kr;
      bf16x8 b1 = *(const bf16x8*)(kr + 32);
      f32x4 z = __builtin_amdgcn_mfma_f32_16x16x32_bf16(a0, b0, fz, 0, 0, 0);
      l[sub] = __builtin_amdgcn_mfma_f32_16x16x32_bf16(a1, b1, z, 0, 0, 0);
    }
#pragma unroll
    for (int sub = 0; sub < 4; sub++)
#pragma unroll
      for (int e = 0; e < 4; e++) {
        float p = __expf(l[sub][e] * scale - m_[e]) * inv[e];
        cp[(size_t)(g * 4 + e) * Nn + c0 + (sub << 4) + r] = p;
        pb[(g * 4 + e) * 72 + (sub << 4) + r] = (bf16_t)p;
      }
    // PV: A = P (LDS, row-major), B = vT tile (L2)
    bf16x8 pa0 = *(bf16x8*)&pb[r * 72 + g * 8];
    bf16x8 pa1 = *(bf16x8*)&pb[r * 72 + 32 + g * 8];
#pragma unroll
    for (int d0 = 0; d0 < 4; d0++) {
      const bf16_t* vr = &vp[(size_t)((d0 << 4) + r) * Nn + c0 + g * 8];
      bf16x8 vb0 = *(const bf16x8*)vr;
      bf16x8 vb1 = *(const bf16x8*)(vr + 32);
      oacc[d0] = __builtin_amdgcn_mfma_f32_16x16x32_bf16(pa0, vb0, oacc[d0], 0, 0, 0);
      oacc[d0] = __builtin_amdgcn_mfma_f32_16x16x32_bf16(pa1, vb1, oacc[d0], 0, 0, 0);
    }
  }
  // epilogue: O1 bf16 [b*1024+n][h*64+d]
  const int b = bh / Hh, h = bh % Hh;
#pragma unroll
  for (int d0 = 0; d0 < 4; d0++)
#pragma unroll
    for (int e = 0; e < 4; e++)
      O1[(size_t)(b * Nn + row0 + g * 4 + e) * Cc + h * HD + (d0 << 4) + r] =
          (bf16_t)oacc[d0][e];
}

// ---------------- prevv: O2 = prev @ v (streaming GEMM) ------------------
// block: 256 thr (4 waves), 64 rows x 64 cols per block, K = 1024.
__global__ __launch_bounds__(256) void prevv(
    const float* __restrict__ prev, const bf16_t* __restrict__ vT,
    bf16_t* __restrict__ O2) {
  __shared__ bf16_t As[64 * 40];
  const int tid = threadIdx.x, lane = tid & 63, w = tid >> 6;
  const int g = lane >> 4, r = lane & 15;
  const int bh = blockIdx.x >> 4, nt = blockIdx.x & 15;
  const int n0 = nt << 6;
  const float* ap = prev + (size_t)bh * Nn * Nn;
  const bf16_t* vp = vT + (size_t)bh * HD * Nn;
  const int srow = tid >> 2, skof = (tid & 3) << 3;
  const f32x4 fz = {0.f, 0.f, 0.f, 0.f};
  f32x4 acc[4] = {fz, fz, fz, fz};
  for (int k0 = 0; k0 < Nn; k0 += 32) {
    float4 f0 = *(const float4*)&ap[(size_t)(n0 + srow) * Nn + k0 + skof];
    float4 f1 = *(const float4*)&ap[(size_t)(n0 + srow) * Nn + k0 + skof + 4];
    bf16x8 a8;
    a8[0] = (bf16_t)f0.x; a8[1] = (bf16_t)f0.y; a8[2] = (bf16_t)f0.z; a8[3] = (bf16_t)f0.w;
    a8[4] = (bf16_t)f1.x; a8[5] = (bf16_t)f1.y; a8[6] = (bf16_t)f1.z; a8[7] = (bf16_t)f1.w;
    *(bf16x8*)&As[srow * 40 + skof] = a8;
    __syncthreads();
    bf16x8 af = *(const bf16x8*)&As[(w * 16 + r) * 40 + g * 8];
#pragma unroll
    for (int j = 0; j < 4; j++) {
      bf16x8 bf = *(const bf16x8*)&vp[(size_t)((j << 4) + r) * Nn + k0 + g * 8];
      acc[j] = __builtin_amdgcn_mfma_f32_16x16x32_bf16(af, bf, acc[j], 0, 0, 0);
    }
    __syncthreads();
  }
  const int b = bh / Hh, h = bh % Hh;
#pragma unroll
  for (int j = 0; j < 4; j++)
#pragma unroll
    for (int e = 0; e < 4; e++)
      O2[(size_t)(b * Nn + n0 + w * 16 + g * 4 + e) * Cc + h * HD + (j << 4) + r] =
          (bf16_t)acc[j][e];
}

// ---------------- proj GEMM with fused combine in A-staging --------------
// A[row][c] = b0*O1 + b1*O2 + (-b2/N)*vsum   (per-row b's, per-col vsum)
__global__ __launch_bounds__(256) void gemm_proj(
    const bf16_t* __restrict__ O1, const bf16_t* __restrict__ O2,
    const float* __restrict__ bias4, const float* __restrict__ vsum,
    const bf16_t* __restrict__ Bw, const float* __restrict__ pbias,
    float* __restrict__ outF) {
  __shared__ bf16_t As[128 * 40];
  __shared__ bf16_t Bs[128 * 40];
  const int tid = threadIdx.x, lane = tid & 63, w = tid >> 6;
  const int wr = w >> 1, wc = w & 1;
  const int g = lane >> 4, r = lane & 15;
  const int m0 = (blockIdx.x / 6) << 7;
  const int n0 = (blockIdx.x % 6) << 7;
  const f32x4 fz = {0.f, 0.f, 0.f, 0.f};
  f32x4 acc[4][4];
#pragma unroll
  for (int i = 0; i < 4; i++)
#pragma unroll
    for (int j = 0; j < 4; j++) acc[i][j] = fz;

  for (int k0 = 0; k0 < 768; k0 += 32) {
#pragma unroll
    for (int p = 0; p < 2; p++) {
      int idx = tid + (p << 8);
      int row = idx >> 2, kof = (idx & 3) << 3;
      int grow = m0 + row;
      int b = grow >> 10, n = grow & 1023;
      int c = k0 + kof, h = c >> 6;
      bf16x8 o1 = *(const bf16x8*)&O1[(size_t)grow * Cc + c];
      bf16x8 o2 = *(const bf16x8*)&O2[(size_t)grow * Cc + c];
      float4 bv = *(const float4*)&bias4[((size_t)(b * Hh + h) * Nn + n) * 4];
      float4 v0 = *(const float4*)&vsum[b * Cc + c];
      float4 v1 = *(const float4*)&vsum[b * Cc + c + 4];
      float vs[8] = {v0.x, v0.y, v0.z, v0.w, v1.x, v1.y, v1.z, v1.w};
      bf16x8 a;
#pragma unroll
      for (int j = 0; j < 8; j++)
        a[j] = (bf16_t)(bv.x * (float)o1[j] + bv.y * (float)o2[j] + bv.z * vs[j]);
      *(bf16x8*)&As[row * 40 + kof] = a;
      *(bf16x8*)&Bs[row * 40 + kof] = *(const bf16x8*)&Bw[(size_t)(n0 + row) * Cc + k0 + kof];
    }
    __syncthreads();
    bf16x8 af[4], bfv[4];
#pragma unroll
    for (int i = 0; i < 4; i++) af[i] = *(const bf16x8*)&As[(wr * 64 + i * 16 + r) * 40 + g * 8];
#pragma unroll
    for (int j = 0; j < 4; j++) bfv[j] = *(const bf16x8*)&Bs[(wc * 64 + j * 16 + r) * 40 + g * 8];
#pragma unroll
    for (int i = 0; i < 4; i++)
#pragma unroll
      for (int j = 0; j < 4; j++)
        acc[i][j] = __builtin_amdgcn_mfma_f32_16x16x32_bf16(af[i], bfv[j], acc[i][j], 0, 0, 0);
    __syncthreads();
  }
#pragma unroll
  for (int i = 0; i < 4; i++)
#pragma unroll
    for (int j = 0; j < 4; j++) {
      int c = n0 + wc * 64 + j * 16 + r;
#pragma unroll
      for (int e = 0; e < 4; e++) {
        int mrow = m0 + wr * 64 + i * 16 + g * 4 + e;
        outF[(size_t)mrow * Cc + c] = acc[i][j][e] + pbias[c];
      }
    }
}

// -------------------------------------------------------------------------
extern "C" void kernel_launch(void* const* d_in, const int* in_sizes, int n_in,
                              void* d_out, int out_size, void* d_ws, size_t ws_size,
                              hipStream_t stream) {
  const float* x      = (const float*)d_in[0];
  const float* prev   = (const float*)d_in[1];
  const float* qkv_w  = (const float*)d_in[2];
  const float* proj_w = (const float*)d_in[3];
  const float* proj_b = (const float*)d_in[4];
  const float* bp_w1  = (const float*)d_in[5];
  const float* bp_b1  = (const float*)d_in[6];
  const float* bp_w2  = (const float*)d_in[7];
  const float* bp_w2b = (const float*)d_in[8];

  float* out0 = (float*)d_out;
  float* cur  = out0 + OUT0;

  char* ws = (char*)d_ws;
  bf16_t* xb    = (bf16_t*)(ws + 0);          // dead after gemm0 -> O1
  bf16_t* O1b   = (bf16_t*)(ws + 0);          // 6291456
  bf16_t* qwb   = (bf16_t*)(ws + 6291456);    // dead after gemm0 -> vsum
  float*  vsum  = (float*)(ws + 6291456);     // 12288
  bf16_t* pwb   = (bf16_t*)(ws + 9830400);
  bf16_t* qbf   = (bf16_t*)(ws + 11010048);
  bf16_t* kbf   = (bf16_t*)(ws + 17301504);
  bf16_t* vtb   = (bf16_t*)(ws + 23592960);
  float*  bias4 = (float*)(ws + 29884416);
  bf16_t* O2b   = (bf16_t*)(ws + 30670848);   // 6291456 -> end 36962304
  if (ws_size < 36962304) return;

  convert_all<<<5376, 256, 0, stream>>>(x, qkv_w, proj_w, xb, qwb, pwb);
  gemm_bt<0><<<(4096 / 128) * (2304 / 128), 256, 0, stream>>>(
      xb, qwb, 2304, 768, qbf, kbf, vtb, nullptr, nullptr);
  bias_mlp<<<49152 / 8, 256, 0, stream>>>(qbf, kbf, bp_w1, bp_b1, bp_w2, bp_w2b, bias4);
  vsum_k<<<768, 256, 0, stream>>>(vtb, vsum);
  flash_cur<<<768, 256, 0, stream>>>(qbf, kbf, vtb, cur, O1b);
  prevv<<<48 * 16, 256, 0, stream>>>(prev, vtb, O2b);
  gemm_proj<<<32 * 6, 256, 0, stream>>>(O1b, O2b, bias4, vsum, pwb, proj_b, out0);
}

// Round 6
// 308.308 us; speedup vs baseline: 1.0784x; 1.0784x over previous
//
#include <hip/hip_runtime.h>

typedef __bf16 bf16_t;
typedef __bf16 bf16x8 __attribute__((ext_vector_type(8)));
typedef __bf16 bf16x4 __attribute__((ext_vector_type(4)));
typedef float f32x4 __attribute__((ext_vector_type(4)));

static constexpr int Bb = 4, Hh = 12, Nn = 1024, Cc = 768, HD = 64;
static constexpr int OUT0 = Bb * Nn * Cc;  // 3145728 floats

// ---------------- convert fp32 -> bf16 (x, qkv_w, proj_w) ----------------
__global__ __launch_bounds__(256) void convert_all(
    const float* __restrict__ x, const float* __restrict__ qw, const float* __restrict__ pw,
    bf16_t* __restrict__ xb, bf16_t* __restrict__ qwb, bf16_t* __restrict__ pwb) {
  const int NX = (Bb * Nn * Cc) / 4;  // 786432 float4s
  const int NQ = (3 * Cc * Cc) / 4;   // 442368
  int i = blockIdx.x * 256 + threadIdx.x;
  const float4* src;
  bf16_t* dst;
  int off;
  if (i < NX) { src = (const float4*)x; dst = xb; off = i; }
  else if (i < NX + NQ) { src = (const float4*)qw; dst = qwb; off = i - NX; }
  else { src = (const float4*)pw; dst = pwb; off = i - NX - NQ; }
  float4 v = src[off];
  bf16x4 o;
  o[0] = (bf16_t)v.x; o[1] = (bf16_t)v.y; o[2] = (bf16_t)v.z; o[3] = (bf16_t)v.w;
  *(bf16x4*)(dst + (size_t)off * 4) = o;
}

// ---------------- 128x128-tile bf16 MFMA GEMM -----------------------------
template <int MODE>
__global__ __launch_bounds__(256) void gemm_bt(
    const bf16_t* __restrict__ A, const bf16_t* __restrict__ Bm, int N, int K,
    bf16_t* __restrict__ q_bf, bf16_t* __restrict__ k_bf, bf16_t* __restrict__ vT_bf,
    float* __restrict__ outF, const float* __restrict__ bias) {
  __shared__ bf16_t As[128 * 40];
  __shared__ bf16_t Bs[128 * 40];
  const int tid = threadIdx.x;
  const int lane = tid & 63;
  const int w = tid >> 6;
  const int wr = w >> 1, wc = w & 1;
  const int g = lane >> 4, r = lane & 15;
  const int ntiles = N >> 7;
  const int m0 = (blockIdx.x / ntiles) << 7;
  const int n0 = (blockIdx.x % ntiles) << 7;

  const f32x4 fz = {0.f, 0.f, 0.f, 0.f};
  f32x4 acc[4][4];
#pragma unroll
  for (int i = 0; i < 4; i++)
#pragma unroll
    for (int j = 0; j < 4; j++) acc[i][j] = fz;

  for (int k0 = 0; k0 < K; k0 += 32) {
#pragma unroll
    for (int p = 0; p < 2; p++) {
      int idx = tid + (p << 8);
      int row = idx >> 2;
      int kof = (idx & 3) << 3;
      *(bf16x8*)&As[row * 40 + kof] = *(const bf16x8*)&A[(size_t)(m0 + row) * K + k0 + kof];
      *(bf16x8*)&Bs[row * 40 + kof] = *(const bf16x8*)&Bm[(size_t)(n0 + row) * K + k0 + kof];
    }
    __syncthreads();
    bf16x8 af[4], bfv[4];
#pragma unroll
    for (int i = 0; i < 4; i++) af[i] = *(const bf16x8*)&As[(wr * 64 + i * 16 + r) * 40 + g * 8];
#pragma unroll
    for (int j = 0; j < 4; j++) bfv[j] = *(const bf16x8*)&Bs[(wc * 64 + j * 16 + r) * 40 + g * 8];
#pragma unroll
    for (int i = 0; i < 4; i++)
#pragma unroll
      for (int j = 0; j < 4; j++)
        acc[i][j] = __builtin_amdgcn_mfma_f32_16x16x32_bf16(af[i], bfv[j], acc[i][j], 0, 0, 0);
    __syncthreads();
  }

#pragma unroll
  for (int i = 0; i < 4; i++) {
#pragma unroll
    for (int j = 0; j < 4; j++) {
      int c = n0 + wc * 64 + j * 16 + r;
#pragma unroll
      for (int e = 0; e < 4; e++) {
        int mrow = m0 + wr * 64 + i * 16 + g * 4 + e;
        float val = acc[i][j][e];
        if constexpr (MODE == 0) {
          int which = c / 768;
          int cc = c - which * 768;
          int h = cc >> 6, d = cc & 63;
          int b = mrow >> 10, n = mrow & 1023;
          size_t bh = (size_t)(b * Hh + h);
          if (which == 0)      q_bf[(bh * Nn + n) * HD + d] = (bf16_t)val;
          else if (which == 1) k_bf[(bh * Nn + n) * HD + d] = (bf16_t)val;
          else                 vT_bf[(bh * HD + d) * Nn + n] = (bf16_t)val;
        } else {
          outF[(size_t)mrow * N + c] = val + bias[c];
        }
      }
    }
  }
}

// ---------------- per-(b,h,n) bias MLP -> {1+b0, b1, -b2/N, 0} -----------
__global__ __launch_bounds__(256) void bias_mlp(
    const bf16_t* __restrict__ qb, const bf16_t* __restrict__ kb,
    const float* __restrict__ w1, const float* __restrict__ b1,
    const float* __restrict__ w2, const float* __restrict__ b2,
    float* __restrict__ bias4) {
  __shared__ float w1s[32 * 129];
  __shared__ float qks[8][128];
  __shared__ float h1s[8][32];
  const int t = threadIdx.x;
#pragma unroll
  for (int p = 0; p < 16; p++) {
    int idx = p * 256 + t;
    w1s[(idx >> 7) * 129 + (idx & 127)] = w1[idx];
  }
  const int rl = t >> 5, u = t & 31;
  const int rowg = blockIdx.x * 8 + rl;
  {
    int i4 = u * 4;
    const bf16_t* src = (i4 < 64) ? (qb + (size_t)rowg * HD + i4)
                                  : (kb + (size_t)rowg * HD + (i4 - 64));
    bf16x4 vv = *(const bf16x4*)src;
#pragma unroll
    for (int z = 0; z < 4; z++) qks[rl][i4 + z] = (float)vv[z];
  }
  __syncthreads();
  float accv = b1[u];
#pragma unroll 8
  for (int i = 0; i < 128; i++) accv += qks[rl][i] * w1s[u * 129 + i];
  h1s[rl][u] = fmaxf(accv, 0.f);
  __syncthreads();
  if (u < 4) {
    float outv = 0.f;
    if (u < 3) {
      float s = b2[u];
#pragma unroll
      for (int j = 0; j < 32; j++) s += w2[u * 32 + j] * h1s[rl][j];
      float v = fabsf(s);
      outv = (u == 0) ? (1.f + v) : ((u == 1) ? v : -v * (1.f / (float)Nn));
    }
    bias4[(size_t)rowg * 4 + u] = outv;
  }
}

// ---------------- vsum[b][h*64+d] = sum_n v[b,h,n,d] (one wave each) -----
__global__ __launch_bounds__(256) void vsum_k(
    const bf16_t* __restrict__ vT, float* __restrict__ vsum) {
  const int wid = (blockIdx.x * 256 + threadIdx.x) >> 6;  // 0..3071
  const int lane = threadIdx.x & 63;
  const int b = wid / 768, c = wid % 768;
  const int h = c >> 6, d = c & 63;
  const bf16_t* vp = vT + ((size_t)((b * Hh + h) * HD + d)) * Nn + lane * 16;
  bf16x8 v0 = *(const bf16x8*)vp;
  bf16x8 v1 = *(const bf16x8*)(vp + 8);
  float s = 0.f;
#pragma unroll
  for (int j = 0; j < 8; j++) s += (float)v0[j] + (float)v1[j];
#pragma unroll
  for (int sh = 1; sh < 64; sh <<= 1) s += __shfl_xor(s, sh, 64);
  if (lane == 0) vsum[wid] = s;
}

// ---------------- flash_all: softmax -> cur + blended PV -----------------
// Block = 128 thr (2 waves) = one 16-row tile of one bh; wave w owns
// col-half [512w, 512w+512). Pass 1: per-lane online (m,s) — register
// only, no shuffles in the loop; one cross-lane combine + LDS exchange.
// Pass 2: recompute logits, p -> cur (fp32) + LDS transpose; A-fragment
// pre-blend A = b0*P + b1*prev (per-row coefs, row = lane r); single
// MFMA stream vs shared V B-fragments. Epilogue: cross-wave partial sum,
// + b2z*vsum, write blended head-output bf16.
__global__ __launch_bounds__(128, 5) void flash_all(
    const bf16_t* __restrict__ qb, const bf16_t* __restrict__ kb,
    const bf16_t* __restrict__ vT, const float* __restrict__ prev,
    const float* __restrict__ bias4, const float* __restrict__ vsum,
    float* __restrict__ cur, bf16_t* __restrict__ Ob) {
  __shared__ bf16_t pbuf[2][16 * 72];
  __shared__ f32x4 opart[4][64];
  __shared__ float2 stats[2][16];
  const int tile = blockIdx.x;
  const int bh = tile >> 6, mt = tile & 63;
  const int w = threadIdx.x >> 6, lane = threadIdx.x & 63;
  const int g = lane >> 4, r = lane & 15;
  const int row0 = mt << 4;
  const int colbase = w << 9;

  const bf16_t* qp = qb + ((size_t)bh * Nn + row0) * HD;
  const bf16_t* kp = kb + (size_t)bh * Nn * HD;
  const bf16_t* vp = vT + (size_t)bh * HD * Nn;
  // pre-scaled Q fragments (x0.125 is exact in bf16)
  bf16x8 qa0 = *(const bf16x8*)&qp[r * HD + g * 8];
  bf16x8 qa1 = *(const bf16x8*)&qp[r * HD + g * 8 + 32];
  bf16x8 a0, a1;
#pragma unroll
  for (int j = 0; j < 8; j++) {
    a0[j] = (bf16_t)((float)qa0[j] * 0.125f);
    a1[j] = (bf16_t)((float)qa1[j] * 0.125f);
  }

  const f32x4 fz = {0.f, 0.f, 0.f, 0.f};
  float m_[4] = {-3.0e38f, -3.0e38f, -3.0e38f, -3.0e38f};
  float s_[4] = {0.f, 0.f, 0.f, 0.f};

  // ---- pass 1: per-lane online stats (no cross-lane ops in loop) ----
  for (int t = 0; t < 8; t++) {
    const int c0 = colbase + (t << 6);
    f32x4 l[4];
#pragma unroll
    for (int sub = 0; sub < 4; sub++) {
      const bf16_t* kr = &kp[(size_t)(c0 + (sub << 4) + r) * HD + g * 8];
      bf16x8 b0 = *(const bf16x8*)kr;
      bf16x8 b1 = *(const bf16x8*)(kr + 32);
      f32x4 z = __builtin_amdgcn_mfma_f32_16x16x32_bf16(a0, b0, fz, 0, 0, 0);
      l[sub] = __builtin_amdgcn_mfma_f32_16x16x32_bf16(a1, b1, z, 0, 0, 0);
    }
#pragma unroll
    for (int e = 0; e < 4; e++) {
      float tm = fmaxf(fmaxf(l[0][e], l[1][e]), fmaxf(l[2][e], l[3][e]));
      float nm = fmaxf(m_[e], tm);
      float sum = __expf(l[0][e] - nm) + __expf(l[1][e] - nm) +
                  __expf(l[2][e] - nm) + __expf(l[3][e] - nm);
      s_[e] = s_[e] * __expf(m_[e] - nm) + sum;
      m_[e] = nm;
    }
  }
  // cross-lane combine over the 16 r-lanes (once per wave)
#pragma unroll
  for (int sh = 1; sh < 16; sh <<= 1) {
#pragma unroll
    for (int e = 0; e < 4; e++) {
      float mo = __shfl_xor(m_[e], sh, 64);
      float so = __shfl_xor(s_[e], sh, 64);
      float nm = fmaxf(m_[e], mo);
      s_[e] = s_[e] * __expf(m_[e] - nm) + so * __expf(mo - nm);
      m_[e] = nm;
    }
  }
  if (r == 0) {
#pragma unroll
    for (int e = 0; e < 4; e++) {
      float2 v; v.x = m_[e]; v.y = s_[e];
      stats[w][g * 4 + e] = v;
    }
  }
  __syncthreads();
  float inv[4];
#pragma unroll
  for (int e = 0; e < 4; e++) {
    float2 o = stats[1 - w][g * 4 + e];
    float nm = fmaxf(m_[e], o.x);
    float st = s_[e] * __expf(m_[e] - nm) + o.y * __expf(o.x - nm);
    m_[e] = nm;
    inv[e] = 1.f / st;
  }

  // ---- pass 2: recompute, cur write, pre-blended PV ----
  const float4 bvr = *(const float4*)&bias4[((size_t)bh * 1024 + row0 + r) * 4];
  const float b0c = bvr.x, b1c = bvr.y;
  float* cp = cur + (size_t)bh * Nn * Nn + (size_t)row0 * Nn;
  const float* ppv = prev + (size_t)bh * Nn * Nn + (size_t)row0 * Nn;
  bf16_t* pb = pbuf[w];
  f32x4 oacc[4] = {fz, fz, fz, fz};

  for (int t = 0; t < 8; t++) {
    const int c0 = colbase + (t << 6);
    f32x4 l[4];
#pragma unroll
    for (int sub = 0; sub < 4; sub++) {
      const bf16_t* kr = &kp[(size_t)(c0 + (sub << 4) + r) * HD + g * 8];
      bf16x8 b0 = *(const bf16x8*)kr;
      bf16x8 b1 = *(const bf16x8*)(kr + 32);
      f32x4 z = __builtin_amdgcn_mfma_f32_16x16x32_bf16(a0, b0, fz, 0, 0, 0);
      l[sub] = __builtin_amdgcn_mfma_f32_16x16x32_bf16(a1, b1, z, 0, 0, 0);
    }
#pragma unroll
    for (int sub = 0; sub < 4; sub++)
#pragma unroll
      for (int e = 0; e < 4; e++) {
        float p = __expf(l[sub][e] - m_[e]) * inv[e];
        cp[(size_t)(g * 4 + e) * Nn + c0 + (sub << 4) + r] = p;
        pb[(g * 4 + e) * 72 + (sub << 4) + r] = (bf16_t)p;
      }
    bf16x8 pa0 = *(bf16x8*)&pb[r * 72 + g * 8];
    bf16x8 pa1 = *(bf16x8*)&pb[r * 72 + 32 + g * 8];
    const float* pr = &ppv[(size_t)r * Nn + c0 + g * 8];
    float4 q0 = *(const float4*)pr;
    float4 q1 = *(const float4*)(pr + 4);
    float4 q2 = *(const float4*)(pr + 32);
    float4 q3 = *(const float4*)(pr + 36);
    bf16x8 ab0, ab1;
    ab0[0] = (bf16_t)(b0c * (float)pa0[0] + b1c * q0.x);
    ab0[1] = (bf16_t)(b0c * (float)pa0[1] + b1c * q0.y);
    ab0[2] = (bf16_t)(b0c * (float)pa0[2] + b1c * q0.z);
    ab0[3] = (bf16_t)(b0c * (float)pa0[3] + b1c * q0.w);
    ab0[4] = (bf16_t)(b0c * (float)pa0[4] + b1c * q1.x);
    ab0[5] = (bf16_t)(b0c * (float)pa0[5] + b1c * q1.y);
    ab0[6] = (bf16_t)(b0c * (float)pa0[6] + b1c * q1.z);
    ab0[7] = (bf16_t)(b0c * (float)pa0[7] + b1c * q1.w);
    ab1[0] = (bf16_t)(b0c * (float)pa1[0] + b1c * q2.x);
    ab1[1] = (bf16_t)(b0c * (float)pa1[1] + b1c * q2.y);
    ab1[2] = (bf16_t)(b0c * (float)pa1[2] + b1c * q2.z);
    ab1[3] = (bf16_t)(b0c * (float)pa1[3] + b1c * q2.w);
    ab1[4] = (bf16_t)(b0c * (float)pa1[4] + b1c * q3.x);
    ab1[5] = (bf16_t)(b0c * (float)pa1[5] + b1c * q3.y);
    ab1[6] = (bf16_t)(b0c * (float)pa1[6] + b1c * q3.z);
    ab1[7] = (bf16_t)(b0c * (float)pa1[7] + b1c * q3.w);
#pragma unroll
    for (int d0 = 0; d0 < 4; d0++) {
      const bf16_t* vr = &vp[(size_t)((d0 << 4) + r) * Nn + c0 + g * 8];
      bf16x8 vb0 = *(const bf16x8*)vr;
      bf16x8 vb1 = *(const bf16x8*)(vr + 32);
      oacc[d0] = __builtin_amdgcn_mfma_f32_16x16x32_bf16(ab0, vb0, oacc[d0], 0, 0, 0);
      oacc[d0] = __builtin_amdgcn_mfma_f32_16x16x32_bf16(ab1, vb1, oacc[d0], 0, 0, 0);
    }
  }

  // ---- epilogue: cross-wave combine + vsum term + store ----
  if (w == 1) {
#pragma unroll
    for (int d0 = 0; d0 < 4; d0++) opart[d0][lane] = oacc[d0];
  }
  __syncthreads();
  if (w == 0) {
    const int b = bh / Hh, h = bh % Hh;
    float bz[4];
#pragma unroll
    for (int e = 0; e < 4; e++)
      bz[e] = bias4[((size_t)bh * 1024 + row0 + g * 4 + e) * 4 + 2];
#pragma unroll
    for (int d0 = 0; d0 < 4; d0++) {
      float vs = vsum[b * Cc + h * HD + (d0 << 4) + r];
      f32x4 tot = oacc[d0] + opart[d0][lane];
#pragma unroll
      for (int e = 0; e < 4; e++)
        Ob[(size_t)(b * Nn + row0 + g * 4 + e) * Cc + h * HD + (d0 << 4) + r] =
            (bf16_t)(tot[e] + bz[e] * vs);
    }
  }
}

// -------------------------------------------------------------------------
extern "C" void kernel_launch(void* const* d_in, const int* in_sizes, int n_in,
                              void* d_out, int out_size, void* d_ws, size_t ws_size,
                              hipStream_t stream) {
  const float* x      = (const float*)d_in[0];
  const float* prev   = (const float*)d_in[1];
  const float* qkv_w  = (const float*)d_in[2];
  const float* proj_w = (const float*)d_in[3];
  const float* proj_b = (const float*)d_in[4];
  const float* bp_w1  = (const float*)d_in[5];
  const float* bp_b1  = (const float*)d_in[6];
  const float* bp_w2  = (const float*)d_in[7];
  const float* bp_w2b = (const float*)d_in[8];

  float* out0 = (float*)d_out;
  float* cur  = out0 + OUT0;

  char* ws = (char*)d_ws;
  bf16_t* xb    = (bf16_t*)(ws + 0);          // dead after gemm0 -> Ob
  bf16_t* Ob    = (bf16_t*)(ws + 0);          // 6291456
  bf16_t* qwb   = (bf16_t*)(ws + 6291456);    // dead after gemm0 -> vsum
  float*  vsum  = (float*)(ws + 6291456);     // 12288
  bf16_t* pwb   = (bf16_t*)(ws + 9830400);
  bf16_t* qbf   = (bf16_t*)(ws + 11010048);
  bf16_t* kbf   = (bf16_t*)(ws + 17301504);
  bf16_t* vtb   = (bf16_t*)(ws + 23592960);
  float*  bias4 = (float*)(ws + 29884416);    // 786432 -> end 30670848
  if (ws_size < 30670848) return;

  convert_all<<<5376, 256, 0, stream>>>(x, qkv_w, proj_w, xb, qwb, pwb);
  gemm_bt<0><<<(4096 / 128) * (2304 / 128), 256, 0, stream>>>(
      xb, qwb, 2304, 768, qbf, kbf, vtb, nullptr, nullptr);
  bias_mlp<<<49152 / 8, 256, 0, stream>>>(qbf, kbf, bp_w1, bp_b1, bp_w2, bp_w2b, bias4);
  vsum_k<<<768, 256, 0, stream>>>(vtb, vsum);
  flash_all<<<3072, 128, 0, stream>>>(qbf, kbf, vtb, prev, bias4, vsum, cur, Ob);
  gemm_bt<1><<<(4096 / 128) * (768 / 128), 256, 0, stream>>>(
      Ob, pwb, 768, 768, nullptr, nullptr, nullptr, out0, proj_b);
}